// Round 2
// baseline (476.335 us; speedup 1.0000x reference)
//
#include <hip/hip_runtime.h>
#include <stdint.h>

typedef __bf16 bf16_t;
typedef __bf16 bf16x8 __attribute__((ext_vector_type(8)));
typedef float f32x4 __attribute__((ext_vector_type(4)));

#define EPSBN 1e-5f

// ---------------- workspace layout (bytes) ----------------
#define OFF_XP   ((size_t)0)
#define SZ_IMG   ((size_t)8*4356*256*2)          // padded NHWC bf16 image, 66x66
#define OFF_YP   (OFF_XP + SZ_IMG)
#define OFF_WQS  (OFF_YP + SZ_IMG)
#define SZ_WQS   ((size_t)4*1024*2304*2)         // scaled QK conv weights [conv][hd][tap*256+c]
#define OFF_WVT  (OFF_WQS + SZ_WQS)
#define SZ_WVT   ((size_t)2*2304*1024*2)         // scaled V weights transposed [br][k'][hd]
#define OFF_W1B  (OFF_WVT + SZ_WVT)
#define SZ_WO    ((size_t)65536*2)
#define OFF_W2B  (OFF_W1B + SZ_WO)
#define OFF_SHQ  (OFF_W2B + SZ_WO)
#define SZ_SHQ   ((size_t)4096*4)                // BN shift for convs 0..3
#define OFF_SHV  (OFF_SHQ + SZ_SHQ)
#define SZ_SHV   ((size_t)2048*4)                // BN shift for convs 4,5
#define OFF_QK   (OFF_SHV + SZ_SHV)
#define SZ_QK    ((size_t)4*8*1024*1024*2)       // Q1,Q2,K1,K2: [conv][b][hd][tok] bf16
#define OFF_S    (OFF_QK + SZ_QK)
#define SZ_S     ((size_t)2*8*4*65536*4)         // scores f32 [br][b][h][c][d]
#define OFF_PT   (OFF_S + SZ_S)
#define SZ_PT    ((size_t)2*8*4*65536*2)         // p^T bf16 [br][b][h][d][c]  (x0.25, /l folded)
#define OFF_A1   (OFF_PT + SZ_PT)
#define SZ_A1    ((size_t)2*8*256*1024*2)        // A1 bf16 [br][b][e][hd]
#define OFF_WEFF (OFF_A1 + SZ_A1)
#define SZ_WEFF  ((size_t)2*8*256*2304*2)        // Weff bf16 [br][b][e][k']
#define OFF_BIAS (OFF_WEFF + SZ_WEFF)
#define SZ_BIAS  ((size_t)2*8*256*4)
#define WS_NEED  (OFF_BIAS + SZ_BIAS)

__device__ __forceinline__ void gload16(const bf16_t* g, bf16_t* l) {
  __builtin_amdgcn_global_load_lds(
      (const __attribute__((address_space(1))) void*)g,
      (__attribute__((address_space(3))) void*)l,
      16, 0, 0);
}

// staging LDS offsets for the B tile (wave wv owns chunks {wv, wv+4})
__device__ __forceinline__ int lb_off0() { return ((threadIdx.x >> 6)    ) * 512; }
__device__ __forceinline__ int lb_off1() { return ((threadIdx.x >> 6) + 4) * 512; }

// ---------------- GEMM core: 128x128 tile, BK=32, 4 waves ----------------
// C[M,N] += A[M,K] * B[K,N]; A row-major (K contig), B given as B^T row-major (K contig)
// BSRC: 0 = plain matrix B^T; 1 = implicit conv stride-1 from padded NHWC image;
//       2 = implicit conv stride-2.
template<int BSRC>
__device__ __forceinline__ void gemm_core(
    const bf16_t* __restrict__ A, int ldA,
    const bf16_t* __restrict__ B, int ldB,
    int m0, int n0, int KT, f32x4 acc[4][4])
{
  __shared__ bf16_t lA[2][4096];
  __shared__ bf16_t lB[2][4096];
  const int tid  = threadIdx.x;
  const int lane = tid & 63;
  const int wv   = tid >> 6;
  const int wr   = wv >> 1, wc = wv & 1;
  const int r4   = lane >> 2;       // 0..15
  const int k8   = (lane & 3) * 8;  // 0,8,16,24

  // staging chunk pointers: wave wv owns A-chunks {wv, wv+4}, B-chunks {wv, wv+4}
  const bf16_t* gA0 = A + (size_t)(m0 + (wv    )*16 + r4) * ldA + k8;
  const bf16_t* gA1 = A + (size_t)(m0 + (wv + 4)*16 + r4) * ldA + k8;
  const int la0 = (wv    ) * 512;
  const int la1 = (wv + 4) * 512;
  const bf16_t* gB0 = B; const bf16_t* gB1 = B;
  int pix0a = 0, pix0b = 0;
  if (BSRC == 0) {
    gB0 = B + (size_t)(n0 + (wv    )*16 + r4) * ldB + k8;
    gB1 = B + (size_t)(n0 + (wv + 4)*16 + r4) * ldB + k8;
  } else {
    const int tg0 = n0 + (wv    )*16 + r4;
    const int tg1 = n0 + (wv + 4)*16 + r4;
    if (BSRC == 1) {
      pix0a = (tg0 >> 6)*66 + (tg0 & 63);
      pix0b = (tg1 >> 6)*66 + (tg1 & 63);
    } else {
      pix0a = ((tg0 >> 5)*2)*66 + (tg0 & 31)*2;
      pix0b = ((tg1 >> 5)*2)*66 + (tg1 & 31)*2;
    }
  }

#pragma unroll
  for (int i = 0; i < 4; ++i)
#pragma unroll
    for (int j = 0; j < 4; ++j)
      acc[i][j] = f32x4{0.f, 0.f, 0.f, 0.f};

  const int lr = lane & 15;
  const int lk = (lane >> 4) * 8;
  int aidx[4], bidx[4];
#pragma unroll
  for (int f = 0; f < 4; ++f) {
    aidx[f] = (wr*64 + f*16 + lr)*32 + lk;
    bidx[f] = (wc*64 + f*16 + lr)*32 + lk;
  }

  auto stage = [&](int bufp, int kt) {
    const int kb = kt * 32;
    gload16(gA0 + kb, &lA[bufp][la0]);
    gload16(gA1 + kb, &lA[bufp][la1]);
    if (BSRC == 0) {
      gload16(gB0 + kb, &lB[bufp][lb_off0()]);
      gload16(gB1 + kb, &lB[bufp][lb_off1()]);
    } else {
      const int tap = kb >> 8;
      const int ky  = (tap >= 6) ? 2 : ((tap >= 3) ? 1 : 0);
      const int kx  = tap - ky*3;
      const int coff = (kb & 255) + k8;
      const int pshift = ky*66 + kx;
      gload16(B + (size_t)(pix0a + pshift)*256 + coff, &lB[bufp][lb_off0()]);
      gload16(B + (size_t)(pix0b + pshift)*256 + coff, &lB[bufp][lb_off1()]);
    }
  };

  stage(0, 0);
  __syncthreads();
  int buf = 0;
  for (int kt = 0; kt < KT; ++kt) {
    if (kt + 1 < KT) stage(buf ^ 1, kt + 1);
    bf16x8 av[4], bvv[4];
#pragma unroll
    for (int f = 0; f < 4; ++f) av[f]  = *(const bf16x8*)&lA[buf][aidx[f]];
#pragma unroll
    for (int f = 0; f < 4; ++f) bvv[f] = *(const bf16x8*)&lB[buf][bidx[f]];
#pragma unroll
    for (int i = 0; i < 4; ++i)
#pragma unroll
      for (int j = 0; j < 4; ++j)
        acc[i][j] = __builtin_amdgcn_mfma_f32_16x16x32_bf16(av[i], bvv[j], acc[i][j], 0, 0, 0);
    __syncthreads();
    buf ^= 1;
  }
}

// ---------------- pack + pad: [B,4096,256] f32 -> [B,66,66,256] bf16 ----------------
__global__ __launch_bounds__(256) void k_pack(const float* __restrict__ x, const float* __restrict__ y,
                                              bf16_t* __restrict__ xp, bf16_t* __restrict__ yp)
{
  const int p  = blockIdx.x;   // 0..4355
  const int b  = blockIdx.y;
  const int im = blockIdx.z;
  const int c  = threadIdx.x;
  const int i = p / 66, j = p - i*66;
  const float* src = im ? y : x;
  bf16_t* dst = im ? yp : xp;
  float v = 0.f;
  if (i >= 1 && i <= 64 && j >= 1 && j <= 64)
    v = src[((size_t)b*4096 + (size_t)(i-1)*64 + (j-1))*256 + c];
  dst[((size_t)b*4356 + p)*256 + c] = (bf16_t)v;
}

// ---------------- weight prep: QK convs (0..3) ----------------
__global__ __launch_bounds__(256) void k_prep_wq(const float* __restrict__ wcv,
    const float* __restrict__ g, const float* __restrict__ be,
    const float* __restrict__ mu, const float* __restrict__ va,
    bf16_t* __restrict__ wqs, float* __restrict__ shq)
{
  const int blk = blockIdx.x;          // ci*1024 + hd
  __shared__ float lw[2304];
  const float* src = wcv + (size_t)blk * 2304;
  for (int t = threadIdx.x; t < 2304; t += 256) lw[t] = src[t];
  const float sc = g[blk] * rsqrtf(va[blk] + EPSBN);
  if (threadIdx.x == 0) shq[blk] = be[blk] - mu[blk]*sc;
  __syncthreads();
  bf16_t* dst = wqs + (size_t)blk * 2304;
  for (int t = threadIdx.x; t < 2304; t += 256) {
    const int tap = t >> 8, c = t & 255;
    dst[t] = (bf16_t)(lw[c*9 + tap] * sc);
  }
}

// ---------------- weight prep: V convs transposed [br][k'][hd] ----------------
__global__ __launch_bounds__(256) void k_prep_wv(const float* __restrict__ wcv,
    const float* __restrict__ g, const float* __restrict__ va,
    bf16_t* __restrict__ wvT)
{
  const int cch = blockIdx.x;                 // c0 = cch*8
  const int h = blockIdx.y >> 2, dc = blockIdx.y & 3;  // d0 = dc*64
  const int br = blockIdx.z;
  __shared__ float lw[64][72];
  __shared__ float lsc[64];
  const int ci = 4 + br;
  const int c0 = cch*8, d0 = dc*64;
  for (int e = threadIdx.x; e < 64*72; e += 256) {
    const int dd = e / 72, q = e - dd*72;
    lw[dd][q] = wcv[(size_t)(ci*1024 + h*256 + d0 + dd)*2304 + c0*9 + q];
  }
  if (threadIdx.x < 64) {
    const int bnIdx = ci*1024 + h*256 + d0 + threadIdx.x;
    lsc[threadIdx.x] = g[bnIdx] * rsqrtf(va[bnIdx] + EPSBN);
  }
  __syncthreads();
  for (int e = threadIdx.x; e < 72*64; e += 256) {
    const int kq = e >> 6, dd = e & 63;
    const int cc = kq / 9, tap = kq - cc*9;
    const int kp = tap*256 + c0 + cc;
    wvT[(size_t)br*2359296 + (size_t)kp*1024 + h*256 + d0 + dd] =
        (bf16_t)(lw[dd][cc*9 + tap] * lsc[dd]);
  }
}

// ---------------- small prep: w_out -> bf16, shiftV ----------------
__global__ __launch_bounds__(256) void k_small(const float* __restrict__ w1, const float* __restrict__ w2,
    const float* __restrict__ g, const float* __restrict__ be,
    const float* __restrict__ mu, const float* __restrict__ va,
    bf16_t* __restrict__ w1b, bf16_t* __restrict__ w2b, float* __restrict__ shv)
{
  const int idx = blockIdx.x*256 + threadIdx.x;
  if (idx < 65536) {
    w1b[idx] = (bf16_t)w1[idx];
  } else if (idx < 131072) {
    w2b[idx - 65536] = (bf16_t)w2[idx - 65536];
  } else if (idx < 133120) {
    const int t = idx - 131072;           // br*1024 + hd
    const int bnIdx = 4096 + t;           // (4+br)*1024 + hd
    const float sc = g[bnIdx] * rsqrtf(va[bnIdx] + EPSBN);
    shv[t] = be[bnIdx] - mu[bnIdx]*sc;
  }
}

// ---------------- QK convs (stride 2) ----------------
__global__ __launch_bounds__(256) void k_conv_qk(const bf16_t* __restrict__ wqs,
    const bf16_t* __restrict__ xp, const bf16_t* __restrict__ yp,
    bf16_t* __restrict__ qk, const float* __restrict__ shq)
{
  const int bx = blockIdx.x, b = blockIdx.y, ci = blockIdx.z;
  const int mt = bx >> 3, nt = bx & 7;
  const bf16_t* A = wqs + (size_t)ci * 1024 * 2304;
  const bf16_t* img = (((ci == 0) | (ci == 3)) ? xp : yp) + (size_t)b*4356*256;
  f32x4 acc[4][4];
  gemm_core<2>(A, 2304, img, 0, mt*128, nt*128, 72, acc);

  bf16_t* out = qk + (size_t)(ci*8 + b) * 1024 * 1024;
  const float* sh = shq + ci*1024;
  const int lane = threadIdx.x & 63, wv = threadIdx.x >> 6;
  const int wr = wv >> 1, wc = wv & 1;
#pragma unroll
  for (int i = 0; i < 4; ++i) {
    const int row0 = mt*128 + wr*64 + i*16 + ((lane >> 4) << 2);
    const f32x4 s4 = *(const f32x4*)&sh[row0];
#pragma unroll
    for (int j = 0; j < 4; ++j) {
      const int col = nt*128 + wc*64 + j*16 + (lane & 15);
#pragma unroll
      for (int r = 0; r < 4; ++r)
        out[(size_t)(row0 + r)*1024 + col] = (bf16_t)(acc[i][j][r] + s4[r]);
    }
  }
}

// ---------------- score GEMM: s = Q K^T over tokens ----------------
__global__ __launch_bounds__(256) void k_gemm_s(const bf16_t* __restrict__ qk, float* __restrict__ sb)
{
  const int bx = blockIdx.x, by = blockIdx.y, br = blockIdx.z;
  const int mt = bx >> 1, nt = bx & 1;
  const int b = by >> 2, h = by & 3;
  const int ai = (br == 0) ? 1 : 0;   // Q2 / Q1
  const int bi = (br == 0) ? 2 : 3;   // K1 / K2
  const bf16_t* A  = qk + ((size_t)(ai*8 + b)*1024 + h*256) * 1024;
  const bf16_t* Bp = qk + ((size_t)(bi*8 + b)*1024 + h*256) * 1024;
  f32x4 acc[4][4];
  gemm_core<0>(A, 1024, Bp, 1024, mt*128, nt*128, 32, acc);

  float* out = sb + ((size_t)(br*8 + b)*4 + h) * 65536;
  const int lane = threadIdx.x & 63, wv = threadIdx.x >> 6;
  const int wr = wv >> 1, wc = wv & 1;
#pragma unroll
  for (int i = 0; i < 4; ++i) {
    const int row0 = mt*128 + wr*64 + i*16 + ((lane >> 4) << 2);
#pragma unroll
    for (int j = 0; j < 4; ++j) {
      const int col = nt*128 + wc*64 + j*16 + (lane & 15);
#pragma unroll
      for (int r = 0; r < 4; ++r)
        out[(size_t)(row0 + r)*256 + col] = acc[i][j][r];
    }
  }
}

// ---------------- softmax over d, write p^T (x0.25 folded) ----------------
__global__ __launch_bounds__(256) void k_softmax(const float* __restrict__ sb, bf16_t* __restrict__ pt)
{
  const int cc = blockIdx.x;     // 32-row chunk
  const int bh = blockIdx.y;     // b*4 + h
  const int br = blockIdx.z;
  const size_t base = ((size_t)br*32 + bh) * 65536;
  __shared__ bf16_t lp[32][256];
  const int tid = threadIdx.x, lane = tid & 63, wv = tid >> 6;
  for (int r = 0; r < 8; ++r) {
    const int row = wv*8 + r;
    const float* srow = sb + base + (size_t)(cc*32 + row)*256;
    f32x4 v = ((const f32x4*)srow)[lane];
    v *= 0.0625f;                               // scale_attn = 256^-0.5
    float m = fmaxf(fmaxf(v[0], v[1]), fmaxf(v[2], v[3]));
#pragma unroll
    for (int o = 32; o; o >>= 1) m = fmaxf(m, __shfl_xor(m, o));
    const float e0 = __expf(v[0]-m), e1 = __expf(v[1]-m), e2 = __expf(v[2]-m), e3 = __expf(v[3]-m);
    float s = e0+e1+e2+e3;
#pragma unroll
    for (int o = 32; o; o >>= 1) s += __shfl_xor(s, o);
    const float inv = 0.25f / s;                // head-mean folded
    lp[row][lane*4+0] = (bf16_t)(e0*inv);
    lp[row][lane*4+1] = (bf16_t)(e1*inv);
    lp[row][lane*4+2] = (bf16_t)(e2*inv);
    lp[row][lane*4+3] = (bf16_t)(e3*inv);
  }
  __syncthreads();
  bf16_t* dst = pt + base;
  for (int it = 0; it < 32; ++it) {
    const int idx = it*256 + tid;
    const int d = idx >> 5, c = idx & 31;
    dst[(size_t)d*256 + cc*32 + c] = lp[c][d];
  }
}

// ---------------- A-GEMM: A1[e, h*256+d] = w_out @ p (0.25,1/l already in p) ----------------
__global__ __launch_bounds__(256) void k_gemm_a(const bf16_t* __restrict__ w1b, const bf16_t* __restrict__ w2b,
    const bf16_t* __restrict__ pt, bf16_t* __restrict__ a1)
{
  const int bx = blockIdx.x, by = blockIdx.y, br = blockIdx.z;
  const int mt = bx >> 1, nt = bx & 1;
  const int b = by >> 2, h = by & 3;
  const bf16_t* A  = br ? w2b : w1b;
  const bf16_t* Bp = pt + ((size_t)(br*8 + b)*4 + h) * 65536;
  f32x4 acc[4][4];
  gemm_core<0>(A, 256, Bp, 256, mt*128, nt*128, 8, acc);

  bf16_t* out = a1 + (size_t)(br*8 + b)*262144 + h*256;
  const int lane = threadIdx.x & 63, wv = threadIdx.x >> 6;
  const int wr = wv >> 1, wc = wv & 1;
#pragma unroll
  for (int i = 0; i < 4; ++i) {
    const int row0 = mt*128 + wr*64 + i*16 + ((lane >> 4) << 2);
#pragma unroll
    for (int j = 0; j < 4; ++j) {
      const int col = nt*128 + wc*64 + j*16 + (lane & 15);
#pragma unroll
      for (int r = 0; r < 4; ++r)
        out[(size_t)(row0 + r)*1024 + col] = (bf16_t)acc[i][j][r];
    }
  }
}

// ---------------- bias: Σ_hd A1[e,hd] * shiftV[hd] ----------------
__global__ __launch_bounds__(256) void k_bias(const bf16_t* __restrict__ a1,
    const float* __restrict__ shv, float* __restrict__ bias)
{
  const int wv = threadIdx.x >> 6, lane = threadIdx.x & 63;
  const int e = blockIdx.x*4 + wv;
  const int b = blockIdx.y, br = blockIdx.z;
  const bf16_t* row = a1 + ((size_t)(br*8 + b)*256 + e)*1024;
  const float* sv = shv + br*1024;
  float acc = 0.f;
#pragma unroll
  for (int t = 0; t < 16; ++t) {
    const int idx = t*64 + lane;
    acc += (float)row[idx] * sv[idx];
  }
#pragma unroll
  for (int o = 32; o; o >>= 1) acc += __shfl_xor(acc, o);
  if (lane == 0) bias[(size_t)(br*8 + b)*256 + e] = acc;
}

// ---------------- Weff GEMM: Weff = A1 @ WvS ----------------
__global__ __launch_bounds__(256) void k_gemm_weff(const bf16_t* __restrict__ a1,
    const bf16_t* __restrict__ wvT, bf16_t* __restrict__ weff)
{
  const int bx = blockIdx.x, b = blockIdx.y, br = blockIdx.z;
  const int mt = bx / 18, nt = bx - mt*18;
  const bf16_t* A  = a1 + (size_t)(br*8 + b)*262144;
  const bf16_t* Bp = wvT + (size_t)br*2359296;
  f32x4 acc[4][4];
  gemm_core<0>(A, 1024, Bp, 1024, mt*128, nt*128, 32, acc);

  bf16_t* out = weff + (size_t)(br*8 + b)*589824;
  const int lane = threadIdx.x & 63, wv = threadIdx.x >> 6;
  const int wr = wv >> 1, wc = wv & 1;
#pragma unroll
  for (int i = 0; i < 4; ++i) {
    const int row0 = mt*128 + wr*64 + i*16 + ((lane >> 4) << 2);
#pragma unroll
    for (int j = 0; j < 4; ++j) {
      const int col = nt*128 + wc*64 + j*16 + (lane & 15);
#pragma unroll
      for (int r = 0; r < 4; ++r)
        out[(size_t)(row0 + r)*2304 + col] = (bf16_t)acc[i][j][r];
    }
  }
}

// ---------------- output convs (stride 1, per-batch weights), write o[b][tok][e] f32 ----------------
__global__ __launch_bounds__(256) void k_conv_out(const bf16_t* __restrict__ weff,
    const bf16_t* __restrict__ xp, const bf16_t* __restrict__ yp,
    const float* __restrict__ bias, float* __restrict__ dout)
{
  const int bx = blockIdx.x, b = blockIdx.y, br = blockIdx.z;
  const int mt = bx >> 5, nt = bx & 31;
  const bf16_t* A = weff + (size_t)(br*8 + b)*589824;
  const bf16_t* img = ((br == 0) ? yp : xp) + (size_t)b*4356*256;   // o1 from y, o2 from x
  f32x4 acc[4][4];
  gemm_core<1>(A, 2304, img, 0, mt*128, nt*128, 72, acc);

  float* outp = dout + (size_t)br*8388608 + (size_t)b*1048576;
  const float* bp = bias + (size_t)(br*8 + b)*256;
  const int lane = threadIdx.x & 63, wv = threadIdx.x >> 6;
  const int wr = wv >> 1, wc = wv & 1;
#pragma unroll
  for (int i = 0; i < 4; ++i) {
    const int e0 = mt*128 + wr*64 + i*16 + ((lane >> 4) << 2);
    const f32x4 bv4 = *(const f32x4*)&bp[e0];
#pragma unroll
    for (int j = 0; j < 4; ++j) {
      const int tok = nt*128 + wc*64 + j*16 + (lane & 15);
      f32x4 v = acc[i][j] + bv4;
      *(f32x4*)&outp[(size_t)tok*256 + e0] = v;
    }
  }
}

// ---------------- host ----------------
extern "C" void kernel_launch(void* const* d_in, const int* in_sizes, int n_in,
                              void* d_out, int out_size, void* d_ws, size_t ws_size,
                              hipStream_t stream)
{
  (void)in_sizes; (void)n_in; (void)out_size;
  const float* x   = (const float*)d_in[0];
  const float* y   = (const float*)d_in[1];
  const float* wcv = (const float*)d_in[2];
  const float* bg  = (const float*)d_in[3];
  const float* bb  = (const float*)d_in[4];
  const float* bm  = (const float*)d_in[5];
  const float* bvv = (const float*)d_in[6];
  const float* w1  = (const float*)d_in[7];
  const float* w2  = (const float*)d_in[8];
  float* out = (float*)d_out;
  char* ws = (char*)d_ws;
  if (ws_size < WS_NEED) return;

  bf16_t* xp   = (bf16_t*)(ws + OFF_XP);
  bf16_t* yp   = (bf16_t*)(ws + OFF_YP);
  bf16_t* wqs  = (bf16_t*)(ws + OFF_WQS);
  bf16_t* wvT  = (bf16_t*)(ws + OFF_WVT);
  bf16_t* w1b  = (bf16_t*)(ws + OFF_W1B);
  bf16_t* w2b  = (bf16_t*)(ws + OFF_W2B);
  float*  shq  = (float*)(ws + OFF_SHQ);
  float*  shv  = (float*)(ws + OFF_SHV);
  bf16_t* qk   = (bf16_t*)(ws + OFF_QK);
  float*  sb   = (float*)(ws + OFF_S);
  bf16_t* pt   = (bf16_t*)(ws + OFF_PT);
  bf16_t* a1   = (bf16_t*)(ws + OFF_A1);
  bf16_t* weff = (bf16_t*)(ws + OFF_WEFF);
  float*  bias = (float*)(ws + OFF_BIAS);

  k_pack    <<<dim3(4356, 8, 2), 256, 0, stream>>>(x, y, xp, yp);
  k_prep_wq <<<dim3(4096), 256, 0, stream>>>(wcv, bg, bb, bm, bvv, wqs, shq);
  k_prep_wv <<<dim3(32, 16, 2), 256, 0, stream>>>(wcv, bg, bvv, wvT);
  k_small   <<<dim3(520), 256, 0, stream>>>(w1, w2, bg, bb, bm, bvv, w1b, w2b, shv);
  k_conv_qk <<<dim3(64, 8, 4), 256, 0, stream>>>(wqs, xp, yp, qk, shq);
  k_gemm_s  <<<dim3(4, 32, 2), 256, 0, stream>>>(qk, sb);
  k_softmax <<<dim3(8, 32, 2), 256, 0, stream>>>(sb, pt);
  k_gemm_a  <<<dim3(4, 32, 2), 256, 0, stream>>>(w1b, w2b, pt, a1);
  k_bias    <<<dim3(64, 8, 2), 256, 0, stream>>>(a1, shv, bias);
  k_gemm_weff<<<dim3(36, 8, 2), 256, 0, stream>>>(a1, wvT, weff);
  k_conv_out<<<dim3(64, 8, 2), 256, 0, stream>>>(weff, xp, yp, bias, out);
}

// Round 3
// 367.429 us; speedup vs baseline: 1.2964x; 1.2964x over previous
//
#include <hip/hip_runtime.h>
#include <stdint.h>

typedef __bf16 bf16_t;
typedef __bf16 bf16x8 __attribute__((ext_vector_type(8)));
typedef float f32x4 __attribute__((ext_vector_type(4)));

#define EPSBN 1e-5f

// ---------------- workspace layout (bytes) ----------------
#define OFF_XP   ((size_t)0)
#define SZ_IMG   ((size_t)8*4356*256*2)          // padded NHWC bf16 image, 66x66
#define OFF_YP   (OFF_XP + SZ_IMG)
#define OFF_WQS  (OFF_YP + SZ_IMG)
#define SZ_WQS   ((size_t)4*1024*2304*2)         // scaled QK conv weights [conv][hd][tap*256+c]
#define OFF_WVT  (OFF_WQS + SZ_WQS)
#define SZ_WVT   ((size_t)2*2304*1024*2)         // scaled V weights transposed [br][k'][hd]
#define OFF_W1B  (OFF_WVT + SZ_WVT)
#define SZ_WO    ((size_t)65536*2)
#define OFF_W2B  (OFF_W1B + SZ_WO)
#define OFF_SHQ  (OFF_W2B + SZ_WO)
#define SZ_SHQ   ((size_t)4096*4)                // BN shift for convs 0..3
#define OFF_SHV  (OFF_SHQ + SZ_SHQ)
#define SZ_SHV   ((size_t)2048*4)                // BN shift for convs 4,5
#define OFF_QK   (OFF_SHV + SZ_SHV)
#define SZ_QK    ((size_t)4*8*1024*1024*2)       // Q1,Q2,K1,K2: [conv][b][hd][tok] bf16
#define OFF_S    (OFF_QK + SZ_QK)
#define SZ_S     ((size_t)2*8*4*65536*4)         // scores f32 [br][b][h][c][d]
#define OFF_PT   (OFF_S + SZ_S)
#define SZ_PT    ((size_t)2*8*4*65536*2)         // p^T bf16 [br][b][h][d][c]  (x0.25, /l folded)
#define OFF_A1   (OFF_PT + SZ_PT)
#define SZ_A1    ((size_t)2*8*256*1024*2)        // A1 bf16 [br][b][e][hd]
#define OFF_WEFF (OFF_A1 + SZ_A1)
#define SZ_WEFF  ((size_t)2*8*256*2304*2)        // Weff bf16 [br][b][e][k']
#define OFF_BIAS (OFF_WEFF + SZ_WEFF)
#define SZ_BIAS  ((size_t)2*8*256*4)
#define WS_NEED  (OFF_BIAS + SZ_BIAS)

__device__ __forceinline__ void gload16(const bf16_t* g, bf16_t* l) {
  __builtin_amdgcn_global_load_lds(
      (const __attribute__((address_space(1))) void*)g,
      (__attribute__((address_space(3))) void*)l,
      16, 0, 0);
}

// staging LDS offsets for the B tile (wave wv owns chunks {wv, wv+4})
__device__ __forceinline__ int lb_off0() { return ((threadIdx.x >> 6)    ) * 512; }
__device__ __forceinline__ int lb_off1() { return ((threadIdx.x >> 6) + 4) * 512; }

// ---------------- old GEMM core: 128x128 tile, BK=32, 4 waves (small GEMMs) ----------------
template<int BSRC>
__device__ __forceinline__ void gemm_core(
    const bf16_t* __restrict__ A, int ldA,
    const bf16_t* __restrict__ B, int ldB,
    int m0, int n0, int KT, f32x4 acc[4][4])
{
  __shared__ bf16_t lA[2][4096];
  __shared__ bf16_t lB[2][4096];
  const int tid  = threadIdx.x;
  const int lane = tid & 63;
  const int wv   = tid >> 6;
  const int wr   = wv >> 1, wc = wv & 1;
  const int r4   = lane >> 2;       // 0..15
  const int k8   = (lane & 3) * 8;  // 0,8,16,24

  const bf16_t* gA0 = A + (size_t)(m0 + (wv    )*16 + r4) * ldA + k8;
  const bf16_t* gA1 = A + (size_t)(m0 + (wv + 4)*16 + r4) * ldA + k8;
  const int la0 = (wv    ) * 512;
  const int la1 = (wv + 4) * 512;
  const bf16_t* gB0 = B + (size_t)(n0 + (wv    )*16 + r4) * ldB + k8;
  const bf16_t* gB1 = B + (size_t)(n0 + (wv + 4)*16 + r4) * ldB + k8;
  (void)BSRC;

#pragma unroll
  for (int i = 0; i < 4; ++i)
#pragma unroll
    for (int j = 0; j < 4; ++j)
      acc[i][j] = f32x4{0.f, 0.f, 0.f, 0.f};

  const int lr = lane & 15;
  const int lk = (lane >> 4) * 8;
  int aidx[4], bidx[4];
#pragma unroll
  for (int f = 0; f < 4; ++f) {
    aidx[f] = (wr*64 + f*16 + lr)*32 + lk;
    bidx[f] = (wc*64 + f*16 + lr)*32 + lk;
  }

  auto stage = [&](int bufp, int kt) {
    const int kb = kt * 32;
    gload16(gA0 + kb, &lA[bufp][la0]);
    gload16(gA1 + kb, &lA[bufp][la1]);
    gload16(gB0 + kb, &lB[bufp][lb_off0()]);
    gload16(gB1 + kb, &lB[bufp][lb_off1()]);
  };

  stage(0, 0);
  __syncthreads();
  int buf = 0;
  for (int kt = 0; kt < KT; ++kt) {
    if (kt + 1 < KT) stage(buf ^ 1, kt + 1);
    bf16x8 av[4], bvv[4];
#pragma unroll
    for (int f = 0; f < 4; ++f) av[f]  = *(const bf16x8*)&lA[buf][aidx[f]];
#pragma unroll
    for (int f = 0; f < 4; ++f) bvv[f] = *(const bf16x8*)&lB[buf][bidx[f]];
#pragma unroll
    for (int i = 0; i < 4; ++i)
#pragma unroll
      for (int j = 0; j < 4; ++j)
        acc[i][j] = __builtin_amdgcn_mfma_f32_16x16x32_bf16(av[i], bvv[j], acc[i][j], 0, 0, 0);
    __syncthreads();
    buf ^= 1;
  }
}

// ================= 256x256 8-phase conv GEMM core =================
// C[M,N] = A[M,K=2304] * conv-im2col(img), K-tile BK=64, NT=36 tiles.
// 8 waves (2M x 4N), per-wave C = 128x64 (8 m-frags x 4 n-frags).
// LDS: [2 buf][2 mat][2 khalf][256 rows][32 k] bf16 = 128 KiB.
// Swizzle sigma: 16B-slot ks ^= (row&6)>>1, applied on pre-swizzled global
// source (writer) and on ds_read address (reader).
// Phases per K-tile: q=(kh,nh) in (0,0),(0,1),(1,0),(1,1); one half retires
// per phase; stage rotation targets just-retired slots; vmcnt(4) at q2.
template<int STRIDE>
__device__ __forceinline__ void conv256_core(
    const bf16_t* __restrict__ A, const bf16_t* __restrict__ img,
    int m0, int n0, f32x4 acc[8][4])
{
  __shared__ bf16_t lds[2][2][2][8192];   // [buf][mat][kh][256*32]
  const int tid  = threadIdx.x;           // 0..511
  const int lane = tid & 63;
  const int w    = tid >> 6;
  const int wm   = w >> 2;                // 0..1
  const int wn   = w & 3;                 // 0..3

#pragma unroll
  for (int f = 0; f < 8; ++f)
#pragma unroll
    for (int j = 0; j < 4; ++j)
      acc[f][j] = f32x4{0.f, 0.f, 0.f, 0.f};

  // ---- staging precompute (writer side, pre-swizzled source) ----
  const int srow = tid >> 2;                           // row within half, issue 0
  const int ksX  = (tid & 3) ^ ((tid >> 3) & 3);       // sigma'd k-slot
  const bf16_t* gA0 = A + (size_t)(m0 + srow      ) * 2304 + ksX*8;
  const bf16_t* gA1 = A + (size_t)(m0 + srow + 128) * 2304 + ksX*8;
  const int tk0 = n0 + srow, tk1 = tk0 + 128;
  int px0, px1;
  if (STRIDE == 1) { px0 = (tk0>>6)*66 + (tk0&63);      px1 = (tk1>>6)*66 + (tk1&63); }
  else             { px0 = ((tk0>>5)*2)*66 + (tk0&31)*2; px1 = ((tk1>>5)*2)*66 + (tk1&31)*2; }
  const bf16_t* gB0 = img + (size_t)px0*256 + ksX*8;
  const bf16_t* gB1 = img + (size_t)px1*256 + ksX*8;

  auto stageA = [&](int buf, int kh, int T) {
    const int kb = T*64 + kh*32;
    bf16_t* d = &lds[buf][0][kh][0] + tid*8;
    gload16(gA0 + kb, d);
    gload16(gA1 + kb, d + 4096);
  };
  auto stageB = [&](int buf, int kh, int T) {
    const int tap = T >> 2;
    const int ky  = (tap >= 6) ? 2 : ((tap >= 3) ? 1 : 0);
    const int kx  = tap - ky*3;
    const int ps  = (ky*66 + kx)*256 + (T & 3)*64 + kh*32;
    bf16_t* d = &lds[buf][1][kh][0] + tid*8;
    gload16(gB0 + ps, d);
    gload16(gB1 + ps, d + 4096);
  };

  // ---- reader precompute (swizzled ds_read offsets, elements) ----
  const int lr    = lane & 15;
  const int slotS = (lane >> 4) ^ ((lane & 6) >> 1);
  int offA[8], offB[4];
#pragma unroll
  for (int f = 0; f < 8; ++f) offA[f] = (wm*128 + f*16 + lr)*32 + slotS*8;
#pragma unroll
  for (int nf = 0; nf < 4; ++nf) offB[nf] = (wn*64 + nf*16 + lr)*32 + slotS*8;

  // ---- prologue: tile0 complete + tile1 {Ak0,Bk0,Ak1}; Bk1(1) staged at p0 ----
  stageA(0,0,0); stageB(0,0,0); stageA(0,1,0); stageB(0,1,0);
  stageA(1,0,1); stageB(1,0,1); stageA(1,1,1);
  __builtin_amdgcn_sched_barrier(0);
  asm volatile("s_waitcnt vmcnt(6)" ::: "memory");
  __builtin_amdgcn_sched_barrier(0);
  __builtin_amdgcn_s_barrier();
  __builtin_amdgcn_sched_barrier(0);

  const int NT = 36;
  for (int T = 0; T < NT; ++T) {
    const int buf = T & 1;
    const bool tail = (T >= NT - 2);
    bf16x8 av[8];
#pragma unroll
    for (int q = 0; q < 4; ++q) {
      const int kh = q >> 1;
      const int nh = q & 1;
      // ds reads (A-frags only on nh==0, reused at nh==1)
      if (nh == 0) {
#pragma unroll
        for (int f = 0; f < 8; ++f)
          av[f] = *(const bf16x8*)(&lds[buf][0][kh][0] + offA[f]);
      }
      bf16x8 bv0 = *(const bf16x8*)(&lds[buf][1][kh][0] + offB[nh*2+0]);
      bf16x8 bv1 = *(const bf16x8*)(&lds[buf][1][kh][0] + offB[nh*2+1]);
      // stage rotation (slot retired in previous phase)
      if      (q == 0) { if (T+1 < NT) stageB(buf^1, 1, T+1); }
      else if (q == 1) { if (T+2 < NT) stageA(buf,   0, T+2); }
      else if (q == 2) { if (T+2 < NT) stageB(buf,   0, T+2); }
      else             { if (T+2 < NT) stageA(buf,   1, T+2); }
      if (q == 2) {
        __builtin_amdgcn_sched_barrier(0);
        if (tail) asm volatile("s_waitcnt vmcnt(0)" ::: "memory");
        else      asm volatile("s_waitcnt vmcnt(4)" ::: "memory");
        __builtin_amdgcn_sched_barrier(0);
      }
      __builtin_amdgcn_s_barrier();
      asm volatile("s_waitcnt lgkmcnt(0)" ::: "memory");
      __builtin_amdgcn_sched_barrier(0);
      __builtin_amdgcn_s_setprio(1);
#pragma unroll
      for (int f = 0; f < 8; ++f) {
        acc[f][nh*2+0] = __builtin_amdgcn_mfma_f32_16x16x32_bf16(av[f], bv0, acc[f][nh*2+0], 0,0,0);
        acc[f][nh*2+1] = __builtin_amdgcn_mfma_f32_16x16x32_bf16(av[f], bv1, acc[f][nh*2+1], 0,0,0);
      }
      __builtin_amdgcn_s_setprio(0);
      __builtin_amdgcn_s_barrier();
      __builtin_amdgcn_sched_barrier(0);
    }
  }
}

// ---------------- QK convs (stride 2), 256^2 8-phase ----------------
__global__ __launch_bounds__(512) void k_conv_qk2(const bf16_t* __restrict__ wqs,
    const bf16_t* __restrict__ xp, const bf16_t* __restrict__ yp,
    bf16_t* __restrict__ qk, const float* __restrict__ shq)
{
  const int bx = blockIdx.x, b = blockIdx.y, ci = blockIdx.z;
  const int mt = bx >> 2, nt = bx & 3;
  const int m0 = mt*256, n0 = nt*256;
  const bf16_t* A = wqs + (size_t)ci * 1024 * 2304;
  const bf16_t* img = (((ci == 0) | (ci == 3)) ? xp : yp) + (size_t)b*4356*256;
  f32x4 acc[8][4];
  conv256_core<2>(A, img, m0, n0, acc);

  bf16_t* out = qk + (size_t)(ci*8 + b) * 1024 * 1024;
  const float* sh = shq + ci*1024;
  const int lane = threadIdx.x & 63, w = threadIdx.x >> 6;
  const int wm = w >> 2, wn = w & 3;
#pragma unroll
  for (int f = 0; f < 8; ++f) {
    const int row0 = m0 + wm*128 + f*16 + ((lane >> 4) << 2);
    const f32x4 s4 = *(const f32x4*)&sh[row0];
#pragma unroll
    for (int nf = 0; nf < 4; ++nf) {
      const int col = n0 + wn*64 + nf*16 + (lane & 15);
#pragma unroll
      for (int r = 0; r < 4; ++r)
        out[(size_t)(row0 + r)*1024 + col] = (bf16_t)(acc[f][nf][r] + s4[r]);
    }
  }
}

// ---------------- output convs (stride 1, per-batch weights), 256^2 8-phase ----------------
__global__ __launch_bounds__(512) void k_conv_out2(const bf16_t* __restrict__ weff,
    const bf16_t* __restrict__ xp, const bf16_t* __restrict__ yp,
    const float* __restrict__ bias, float* __restrict__ dout)
{
  const int nt = blockIdx.x, b = blockIdx.y, br = blockIdx.z;
  const int n0 = nt*256;
  const bf16_t* A = weff + (size_t)(br*8 + b)*589824;
  const bf16_t* img = ((br == 0) ? yp : xp) + (size_t)b*4356*256;   // o1 from y, o2 from x
  f32x4 acc[8][4];
  conv256_core<1>(A, img, 0, n0, acc);

  float* outp = dout + (size_t)br*8388608 + (size_t)b*1048576;
  const float* bp = bias + (size_t)(br*8 + b)*256;
  const int lane = threadIdx.x & 63, w = threadIdx.x >> 6;
  const int wm = w >> 2, wn = w & 3;
#pragma unroll
  for (int f = 0; f < 8; ++f) {
    const int e0 = wm*128 + f*16 + ((lane >> 4) << 2);
    const f32x4 bv4 = *(const f32x4*)&bp[e0];
#pragma unroll
    for (int nf = 0; nf < 4; ++nf) {
      const int tok = n0 + wn*64 + nf*16 + (lane & 15);
      f32x4 v = acc[f][nf] + bv4;
      *(f32x4*)&outp[(size_t)tok*256 + e0] = v;
    }
  }
}

// ---------------- pack + pad: [B,4096,256] f32 -> [B,66,66,256] bf16 ----------------
__global__ __launch_bounds__(256) void k_pack(const float* __restrict__ x, const float* __restrict__ y,
                                              bf16_t* __restrict__ xp, bf16_t* __restrict__ yp)
{
  const int p  = blockIdx.x;   // 0..4355
  const int b  = blockIdx.y;
  const int im = blockIdx.z;
  const int c  = threadIdx.x;
  const int i = p / 66, j = p - i*66;
  const float* src = im ? y : x;
  bf16_t* dst = im ? yp : xp;
  float v = 0.f;
  if (i >= 1 && i <= 64 && j >= 1 && j <= 64)
    v = src[((size_t)b*4096 + (size_t)(i-1)*64 + (j-1))*256 + c];
  dst[((size_t)b*4356 + p)*256 + c] = (bf16_t)v;
}

// ---------------- weight prep: QK convs (0..3) ----------------
__global__ __launch_bounds__(256) void k_prep_wq(const float* __restrict__ wcv,
    const float* __restrict__ g, const float* __restrict__ be,
    const float* __restrict__ mu, const float* __restrict__ va,
    bf16_t* __restrict__ wqs, float* __restrict__ shq)
{
  const int blk = blockIdx.x;          // ci*1024 + hd
  __shared__ float lw[2304];
  const float* src = wcv + (size_t)blk * 2304;
  for (int t = threadIdx.x; t < 2304; t += 256) lw[t] = src[t];
  const float sc = g[blk] * rsqrtf(va[blk] + EPSBN);
  if (threadIdx.x == 0) shq[blk] = be[blk] - mu[blk]*sc;
  __syncthreads();
  bf16_t* dst = wqs + (size_t)blk * 2304;
  for (int t = threadIdx.x; t < 2304; t += 256) {
    const int tap = t >> 8, c = t & 255;
    dst[t] = (bf16_t)(lw[c*9 + tap] * sc);
  }
}

// ---------------- weight prep: V convs transposed [br][k'][hd] ----------------
__global__ __launch_bounds__(256) void k_prep_wv(const float* __restrict__ wcv,
    const float* __restrict__ g, const float* __restrict__ va,
    bf16_t* __restrict__ wvT)
{
  const int cch = blockIdx.x;                 // c0 = cch*8
  const int h = blockIdx.y >> 2, dc = blockIdx.y & 3;  // d0 = dc*64
  const int br = blockIdx.z;
  __shared__ float lw[64][72];
  __shared__ float lsc[64];
  const int ci = 4 + br;
  const int c0 = cch*8, d0 = dc*64;
  for (int e = threadIdx.x; e < 64*72; e += 256) {
    const int dd = e / 72, q = e - dd*72;
    lw[dd][q] = wcv[(size_t)(ci*1024 + h*256 + d0 + dd)*2304 + c0*9 + q];
  }
  if (threadIdx.x < 64) {
    const int bnIdx = ci*1024 + h*256 + d0 + threadIdx.x;
    lsc[threadIdx.x] = g[bnIdx] * rsqrtf(va[bnIdx] + EPSBN);
  }
  __syncthreads();
  for (int e = threadIdx.x; e < 72*64; e += 256) {
    const int kq = e >> 6, dd = e & 63;
    const int cc = kq / 9, tap = kq - cc*9;
    const int kp = tap*256 + c0 + cc;
    wvT[(size_t)br*2359296 + (size_t)kp*1024 + h*256 + d0 + dd] =
        (bf16_t)(lw[dd][cc*9 + tap] * lsc[dd]);
  }
}

// ---------------- small prep: w_out -> bf16, shiftV ----------------
__global__ __launch_bounds__(256) void k_small(const float* __restrict__ w1, const float* __restrict__ w2,
    const float* __restrict__ g, const float* __restrict__ be,
    const float* __restrict__ mu, const float* __restrict__ va,
    bf16_t* __restrict__ w1b, bf16_t* __restrict__ w2b, float* __restrict__ shv)
{
  const int idx = blockIdx.x*256 + threadIdx.x;
  if (idx < 65536) {
    w1b[idx] = (bf16_t)w1[idx];
  } else if (idx < 131072) {
    w2b[idx - 65536] = (bf16_t)w2[idx - 65536];
  } else if (idx < 133120) {
    const int t = idx - 131072;           // br*1024 + hd
    const int bnIdx = 4096 + t;           // (4+br)*1024 + hd
    const float sc = g[bnIdx] * rsqrtf(va[bnIdx] + EPSBN);
    shv[t] = be[bnIdx] - mu[bnIdx]*sc;
  }
}

// ---------------- score GEMM: s = Q K^T over tokens ----------------
__global__ __launch_bounds__(256) void k_gemm_s(const bf16_t* __restrict__ qk, float* __restrict__ sb)
{
  const int bx = blockIdx.x, by = blockIdx.y, br = blockIdx.z;
  const int mt = bx >> 1, nt = bx & 1;
  const int b = by >> 2, h = by & 3;
  const int ai = (br == 0) ? 1 : 0;   // Q2 / Q1
  const int bi = (br == 0) ? 2 : 3;   // K1 / K2
  const bf16_t* A  = qk + ((size_t)(ai*8 + b)*1024 + h*256) * 1024;
  const bf16_t* Bp = qk + ((size_t)(bi*8 + b)*1024 + h*256) * 1024;
  f32x4 acc[4][4];
  gemm_core<0>(A, 1024, Bp, 1024, mt*128, nt*128, 32, acc);

  float* out = sb + ((size_t)(br*8 + b)*4 + h) * 65536;
  const int lane = threadIdx.x & 63, wv = threadIdx.x >> 6;
  const int wr = wv >> 1, wc = wv & 1;
#pragma unroll
  for (int i = 0; i < 4; ++i) {
    const int row0 = mt*128 + wr*64 + i*16 + ((lane >> 4) << 2);
#pragma unroll
    for (int j = 0; j < 4; ++j) {
      const int col = nt*128 + wc*64 + j*16 + (lane & 15);
#pragma unroll
      for (int r = 0; r < 4; ++r)
        out[(size_t)(row0 + r)*256 + col] = acc[i][j][r];
    }
  }
}

// ---------------- softmax over d, write p^T (x0.25 folded) ----------------
__global__ __launch_bounds__(256) void k_softmax(const float* __restrict__ sb, bf16_t* __restrict__ pt)
{
  const int cc = blockIdx.x;     // 32-row chunk
  const int bh = blockIdx.y;     // b*4 + h
  const int br = blockIdx.z;
  const size_t base = ((size_t)br*32 + bh) * 65536;
  __shared__ bf16_t lp[32][256];
  const int tid = threadIdx.x, lane = tid & 63, wv = tid >> 6;
  for (int r = 0; r < 8; ++r) {
    const int row = wv*8 + r;
    const float* srow = sb + base + (size_t)(cc*32 + row)*256;
    f32x4 v = ((const f32x4*)srow)[lane];
    v *= 0.0625f;                               // scale_attn = 256^-0.5
    float m = fmaxf(fmaxf(v[0], v[1]), fmaxf(v[2], v[3]));
#pragma unroll
    for (int o = 32; o; o >>= 1) m = fmaxf(m, __shfl_xor(m, o));
    const float e0 = __expf(v[0]-m), e1 = __expf(v[1]-m), e2 = __expf(v[2]-m), e3 = __expf(v[3]-m);
    float s = e0+e1+e2+e3;
#pragma unroll
    for (int o = 32; o; o >>= 1) s += __shfl_xor(s, o);
    const float inv = 0.25f / s;                // head-mean folded
    lp[row][lane*4+0] = (bf16_t)(e0*inv);
    lp[row][lane*4+1] = (bf16_t)(e1*inv);
    lp[row][lane*4+2] = (bf16_t)(e2*inv);
    lp[row][lane*4+3] = (bf16_t)(e3*inv);
  }
  __syncthreads();
  bf16_t* dst = pt + base;
  for (int it = 0; it < 32; ++it) {
    const int idx = it*256 + tid;
    const int d = idx >> 5, c = idx & 31;
    dst[(size_t)d*256 + cc*32 + c] = lp[c][d];
  }
}

// ---------------- A-GEMM: A1[e, h*256+d] = w_out @ p ----------------
__global__ __launch_bounds__(256) void k_gemm_a(const bf16_t* __restrict__ w1b, const bf16_t* __restrict__ w2b,
    const bf16_t* __restrict__ pt, bf16_t* __restrict__ a1)
{
  const int bx = blockIdx.x, by = blockIdx.y, br = blockIdx.z;
  const int mt = bx >> 1, nt = bx & 1;
  const int b = by >> 2, h = by & 3;
  const bf16_t* A  = br ? w2b : w1b;
  const bf16_t* Bp = pt + ((size_t)(br*8 + b)*4 + h) * 65536;
  f32x4 acc[4][4];
  gemm_core<0>(A, 256, Bp, 256, mt*128, nt*128, 8, acc);

  bf16_t* out = a1 + (size_t)(br*8 + b)*262144 + h*256;
  const int lane = threadIdx.x & 63, wv = threadIdx.x >> 6;
  const int wr = wv >> 1, wc = wv & 1;
#pragma unroll
  for (int i = 0; i < 4; ++i) {
    const int row0 = mt*128 + wr*64 + i*16 + ((lane >> 4) << 2);
#pragma unroll
    for (int j = 0; j < 4; ++j) {
      const int col = nt*128 + wc*64 + j*16 + (lane & 15);
#pragma unroll
      for (int r = 0; r < 4; ++r)
        out[(size_t)(row0 + r)*1024 + col] = (bf16_t)acc[i][j][r];
    }
  }
}

// ---------------- bias: sum_hd A1[e,hd] * shiftV[hd] ----------------
__global__ __launch_bounds__(256) void k_bias(const bf16_t* __restrict__ a1,
    const float* __restrict__ shv, float* __restrict__ bias)
{
  const int wv = threadIdx.x >> 6, lane = threadIdx.x & 63;
  const int e = blockIdx.x*4 + wv;
  const int b = blockIdx.y, br = blockIdx.z;
  const bf16_t* row = a1 + ((size_t)(br*8 + b)*256 + e)*1024;
  const float* sv = shv + br*1024;
  float acc = 0.f;
#pragma unroll
  for (int t = 0; t < 16; ++t) {
    const int idx = t*64 + lane;
    acc += (float)row[idx] * sv[idx];
  }
#pragma unroll
  for (int o = 32; o; o >>= 1) acc += __shfl_xor(acc, o);
  if (lane == 0) bias[(size_t)(br*8 + b)*256 + e] = acc;
}

// ---------------- Weff GEMM: Weff = A1 @ WvS ----------------
__global__ __launch_bounds__(256) void k_gemm_weff(const bf16_t* __restrict__ a1,
    const bf16_t* __restrict__ wvT, bf16_t* __restrict__ weff)
{
  const int bx = blockIdx.x, b = blockIdx.y, br = blockIdx.z;
  const int mt = bx / 18, nt = bx - mt*18;
  const bf16_t* A  = a1 + (size_t)(br*8 + b)*262144;
  const bf16_t* Bp = wvT + (size_t)br*2359296;
  f32x4 acc[4][4];
  gemm_core<0>(A, 1024, Bp, 1024, mt*128, nt*128, 32, acc);

  bf16_t* out = weff + (size_t)(br*8 + b)*589824;
  const int lane = threadIdx.x & 63, wv = threadIdx.x >> 6;
  const int wr = wv >> 1, wc = wv & 1;
#pragma unroll
  for (int i = 0; i < 4; ++i) {
    const int row0 = mt*128 + wr*64 + i*16 + ((lane >> 4) << 2);
#pragma unroll
    for (int j = 0; j < 4; ++j) {
      const int col = nt*128 + wc*64 + j*16 + (lane & 15);
#pragma unroll
      for (int r = 0; r < 4; ++r)
        out[(size_t)(row0 + r)*2304 + col] = (bf16_t)acc[i][j][r];
    }
  }
}

// ---------------- host ----------------
extern "C" void kernel_launch(void* const* d_in, const int* in_sizes, int n_in,
                              void* d_out, int out_size, void* d_ws, size_t ws_size,
                              hipStream_t stream)
{
  (void)in_sizes; (void)n_in; (void)out_size;
  const float* x   = (const float*)d_in[0];
  const float* y   = (const float*)d_in[1];
  const float* wcv = (const float*)d_in[2];
  const float* bg  = (const float*)d_in[3];
  const float* bb  = (const float*)d_in[4];
  const float* bm  = (const float*)d_in[5];
  const float* bvv = (const float*)d_in[6];
  const float* w1  = (const float*)d_in[7];
  const float* w2  = (const float*)d_in[8];
  float* out = (float*)d_out;
  char* ws = (char*)d_ws;
  if (ws_size < WS_NEED) return;

  bf16_t* xp   = (bf16_t*)(ws + OFF_XP);
  bf16_t* yp   = (bf16_t*)(ws + OFF_YP);
  bf16_t* wqs  = (bf16_t*)(ws + OFF_WQS);
  bf16_t* wvT  = (bf16_t*)(ws + OFF_WVT);
  bf16_t* w1b  = (bf16_t*)(ws + OFF_W1B);
  bf16_t* w2b  = (bf16_t*)(ws + OFF_W2B);
  float*  shq  = (float*)(ws + OFF_SHQ);
  float*  shv  = (float*)(ws + OFF_SHV);
  bf16_t* qk   = (bf16_t*)(ws + OFF_QK);
  float*  sb   = (float*)(ws + OFF_S);
  bf16_t* pt   = (bf16_t*)(ws + OFF_PT);
  bf16_t* a1   = (bf16_t*)(ws + OFF_A1);
  bf16_t* weff = (bf16_t*)(ws + OFF_WEFF);
  float*  bias = (float*)(ws + OFF_BIAS);

  k_pack     <<<dim3(4356, 8, 2), 256, 0, stream>>>(x, y, xp, yp);
  k_prep_wq  <<<dim3(4096), 256, 0, stream>>>(wcv, bg, bb, bm, bvv, wqs, shq);
  k_prep_wv  <<<dim3(32, 16, 2), 256, 0, stream>>>(wcv, bg, bvv, wvT);
  k_small    <<<dim3(520), 256, 0, stream>>>(w1, w2, bg, bb, bm, bvv, w1b, w2b, shv);
  k_conv_qk2 <<<dim3(16, 8, 4), 512, 0, stream>>>(wqs, xp, yp, qk, shq);
  k_gemm_s   <<<dim3(4, 32, 2), 256, 0, stream>>>(qk, sb);
  k_softmax  <<<dim3(8, 32, 2), 256, 0, stream>>>(sb, pt);
  k_gemm_a   <<<dim3(4, 32, 2), 256, 0, stream>>>(w1b, w2b, pt, a1);
  k_bias     <<<dim3(64, 8, 2), 256, 0, stream>>>(a1, shv, bias);
  k_gemm_weff<<<dim3(36, 8, 2), 256, 0, stream>>>(a1, wvT, weff);
  k_conv_out2<<<dim3(16, 8, 2), 512, 0, stream>>>(weff, xp, yp, bias, out);
}